// Round 1
// baseline (400.507 us; speedup 1.0000x reference)
//
#include <hip/hip_runtime.h>
#include <hip/hip_fp16.h>
#include <math.h>

// Problem constants (fixed by setup_inputs)
#define NB 8
#define NT 8192
#define ND 1024
#define NH 1024
#define CHUNK_ 128
#define SAMPLE_ 16
#define NCHUNK 64          // NT / CHUNK
#define SMAX 2048          // SAMPLE * CHUNK
#define MROWS (NB * SMAX)  // 16384

typedef _Float16 half8 __attribute__((ext_vector_type(8)));
typedef float floatx4 __attribute__((ext_vector_type(4)));

__device__ __forceinline__ unsigned short f2h(float f) {
  return __half_as_ushort(__float2half(f));
}

// ---------------------------------------------------------------------------
// Kernel 1: per-batch chunk selection.
// srcT[b*2048 + s] = time index within batch (chunk*128 + offset), or -1.
// Distinct selected chunks in ascending order == stable argsort of (1-mask).
// ---------------------------------------------------------------------------
__global__ __launch_bounds__(256) void k_select(const int* __restrict__ cidx,
                                                int* __restrict__ srcT) {
  __shared__ int sel[SAMPLE_];
  __shared__ int nsel_s;
  const int b = blockIdx.x;
  if (threadIdx.x == 0) {
    unsigned long long m = 0ull;
    for (int j = 0; j < SAMPLE_; ++j) m |= (1ull << (cidx[b * SAMPLE_ + j] & 63));
    int n = 0;
    for (int c = 0; c < NCHUNK; ++c)
      if ((m >> c) & 1ull) sel[n++] = c;
    nsel_s = n;
  }
  __syncthreads();
  const int n = nsel_s;
  for (int s = threadIdx.x; s < SMAX; s += 256) {
    const int k = s >> 7;
    srcT[b * SMAX + s] = (k < n) ? (sel[k] * CHUNK_ + (s & 127)) : -1;
  }
}

// ---------------------------------------------------------------------------
// Kernel 2: W (D,H) fp32 -> Wt (H,D) fp16  (LDS-tiled transpose, coalesced
// both sides). Wt row-major over [n][k] gives contiguous-K B-fragments.
// ---------------------------------------------------------------------------
__global__ __launch_bounds__(256) void k_wt(const float* __restrict__ W,
                                            unsigned short* __restrict__ Wt) {
  __shared__ unsigned short tile[64][65];  // [h][d], padded
  const int hb = blockIdx.x * 64;
  const int db = blockIdx.y * 64;
  const int c = threadIdx.x & 63;
  const int r0 = threadIdx.x >> 6;
#pragma unroll
  for (int j = 0; j < 16; ++j) {
    const int r = r0 + j * 4;  // d offset
    tile[c][r] = f2h(W[(size_t)(db + r) * NH + hb + c]);
  }
  __syncthreads();
#pragma unroll
  for (int j = 0; j < 16; ++j) {
    const int r = r0 + j * 4;  // h offset
    Wt[(size_t)(hb + r) * ND + db + c] = tile[r][c];
  }
}

// ---------------------------------------------------------------------------
// Kernel 3: gather selected rows of data, fp32 -> fp16, materialize A (M x K).
// One block per output row; 256 threads x 4 elements.
// ---------------------------------------------------------------------------
__global__ __launch_bounds__(256) void k_gatherA(const float* __restrict__ data,
                                                 const int* __restrict__ srcT,
                                                 unsigned short* __restrict__ A) {
  const int row = blockIdx.x;  // 0..16383
  const int t = srcT[row];
  const int d = threadIdx.x * 4;
  ushort4 o;
  if (t < 0) {
    o = make_ushort4(0, 0, 0, 0);
  } else {
    const int b = row >> 11;  // row / 2048
    const float4 v = *(const float4*)(data + ((size_t)b * NT + t) * ND + d);
    o.x = f2h(v.x); o.y = f2h(v.y); o.z = f2h(v.z); o.w = f2h(v.w);
  }
  *(ushort4*)(A + (size_t)row * ND + d) = o;
}

// ---------------------------------------------------------------------------
// Kernel 4: GEMM C = A @ W with fused epilogue (bias + sinusoidal PE, *sqrt(128),
// zero-mask invalid rows). m97 pattern: 128x128 tile, BK=32, 4 waves,
// mfma_f32_16x16x32_f16, global_load_lds width=16 staging.
// ---------------------------------------------------------------------------
__device__ __forceinline__ void gl_lds16(const unsigned short* g, unsigned short* l) {
  __builtin_amdgcn_global_load_lds(
      (const __attribute__((address_space(1))) unsigned int*)g,
      (__attribute__((address_space(3))) unsigned int*)l, 16, 0, 0);
}

__global__ __launch_bounds__(256) void k_gemm(const unsigned short* __restrict__ A,
                                              const unsigned short* __restrict__ Bt,
                                              const float* __restrict__ bias,
                                              const int* __restrict__ srcT,
                                              float* __restrict__ out) {
  __shared__ unsigned short As[128 * 32];  // row-major [m][k]
  __shared__ unsigned short Bs[128 * 32];  // row-major [n][k]
  __shared__ int tS[128];

  const int tid = threadIdx.x;
  const int tile_n = blockIdx.x & 7;   // NH/128 = 8
  const int tile_m = blockIdx.x >> 3;  // MROWS/128 = 128

  if (tid < 128) tS[tid] = srcT[tile_m * 128 + tid];

  const int lane = tid & 63;
  const int wave = tid >> 6;
  const int wm = wave & 1;
  const int wn = wave >> 1;

  floatx4 acc[4][4];
#pragma unroll
  for (int i = 0; i < 4; ++i)
#pragma unroll
    for (int j = 0; j < 4; ++j) acc[i][j] = (floatx4){0.f, 0.f, 0.f, 0.f};

  // Staging: thread i loads 16B chunk at row=i>>2 (+64 for 2nd load), k-chunk=(i&3)*8.
  // LDS dest = wave-uniform base + lane*16B, matching row-major [128][32] layout.
  const int ar = tid >> 2;
  const int ac = (tid & 3) * 8;
  const unsigned short* gA = A + (size_t)(tile_m * 128 + ar) * ND + ac;
  const unsigned short* gB = Bt + (size_t)(tile_n * 128 + ar) * ND + ac;
  unsigned short* lA = As + wave * 512;  // elements (wave*1024 bytes)
  unsigned short* lB = Bs + wave * 512;

  // Fragment LDS offsets: A[m=lane&15][k=(lane>>4)*8 + j], same for B with n.
  const int aoff = (wm * 64 + (lane & 15)) * 32 + (lane >> 4) * 8;
  const int boff = (wn * 64 + (lane & 15)) * 32 + (lane >> 4) * 8;

  for (int kk = 0; kk < ND; kk += 32) {
    __syncthreads();  // protect LDS from overwrite while prior iter still reading
    gl_lds16(gA + kk, lA);
    gl_lds16(gA + 64 * ND + kk, lA + 2048);
    gl_lds16(gB + kk, lB);
    gl_lds16(gB + 64 * ND + kk, lB + 2048);
    __syncthreads();  // compiler emits vmcnt(0) drain before barrier

    half8 af[4], bf[4];
#pragma unroll
    for (int i = 0; i < 4; ++i) af[i] = *(const half8*)(As + aoff + i * 16 * 32);
#pragma unroll
    for (int i = 0; i < 4; ++i) bf[i] = *(const half8*)(Bs + boff + i * 16 * 32);
#pragma unroll
    for (int i = 0; i < 4; ++i)
#pragma unroll
      for (int j = 0; j < 4; ++j)
        acc[i][j] = __builtin_amdgcn_mfma_f32_16x16x32_f16(af[i], bf[j], acc[i][j], 0, 0, 0);
  }

  // Epilogue. C/D layout: col = lane&15, row = (lane>>4)*4 + reg.
  const float scale = 11.313708498984761f;        // sqrt(128)
  const float nl = -9.210340371976184f / 1024.f;  // -ln(10000)/H
  const int colq = lane & 15;
  const int rq = (lane >> 4) * 4;
#pragma unroll
  for (int j = 0; j < 4; ++j) {
    const int gh = tile_n * 128 + wn * 64 + j * 16 + colq;
    const float freq = __expf((float)(gh & ~1) * nl);
    const float bv = bias[gh];
#pragma unroll
    for (int i = 0; i < 4; ++i) {
      const int lrow0 = wm * 64 + i * 16 + rq;
#pragma unroll
      for (int r = 0; r < 4; ++r) {
        const int lrow = lrow0 + r;
        const int t = tS[lrow];
        float v = 0.0f;
        if (t >= 0) {
          const float arg = (float)t * freq;
          const float pe = (gh & 1) ? __cosf(arg) : __sinf(arg);
          v = (acc[i][j][r] + bv + pe) * scale;
        }
        out[(size_t)(tile_m * 128 + lrow) * NH + gh] = v;
      }
    }
  }
}

// ---------------------------------------------------------------------------
extern "C" void kernel_launch(void* const* d_in, const int* in_sizes, int n_in,
                              void* d_out, int out_size, void* d_ws, size_t ws_size,
                              hipStream_t stream) {
  // inputs: state (unused), data, W, b, chunk_idx
  const float* data = (const float*)d_in[1];
  const float* W = (const float*)d_in[2];
  const float* bias = (const float*)d_in[3];
  const int* cidx = (const int*)d_in[4];
  float* out = (float*)d_out;

  char* ws = (char*)d_ws;
  int* srcT = (int*)ws;                                            // 64 KB
  unsigned short* Wt = (unsigned short*)(ws + (64 << 10));         // 2 MB
  unsigned short* A = (unsigned short*)(ws + (64 << 10) + (2 << 20));  // 32 MB

  k_select<<<NB, 256, 0, stream>>>(cidx, srcT);
  k_wt<<<dim3(NH / 64, ND / 64), 256, 0, stream>>>(W, Wt);
  k_gatherA<<<MROWS, 256, 0, stream>>>(data, srcT, A);
  k_gemm<<<(MROWS / 128) * (NH / 128), 256, 0, stream>>>(A, Wt, bias, srcT, out);
}

// Round 2
// 385.115 us; speedup vs baseline: 1.0400x; 1.0400x over previous
//
#include <hip/hip_runtime.h>
#include <hip/hip_fp16.h>
#include <math.h>

// Problem constants (fixed by setup_inputs)
#define NB 8
#define NT 8192
#define ND 1024
#define NH 1024
#define CHUNK_ 128
#define SAMPLE_ 16
#define NCHUNK 64          // NT / CHUNK
#define SMAX 2048          // SAMPLE * CHUNK
#define MROWS (NB * SMAX)  // 16384
#define BK 64              // K-tile (halfs); rows are 128 B -> 8 x 16B chunks

typedef _Float16 half8 __attribute__((ext_vector_type(8)));
typedef float floatx4 __attribute__((ext_vector_type(4)));
typedef unsigned short ushort8 __attribute__((ext_vector_type(8)));

__device__ __forceinline__ unsigned short f2h(float f) {
  return __half_as_ushort(__float2half(f));
}

// ---------------------------------------------------------------------------
// Kernel 1: per-batch chunk selection.
// srcT[b*2048 + s] = time index within batch (chunk*128 + offset), or -1.
// ---------------------------------------------------------------------------
__global__ __launch_bounds__(256) void k_select(const int* __restrict__ cidx,
                                                int* __restrict__ srcT) {
  __shared__ int sel[SAMPLE_];
  __shared__ int nsel_s;
  const int b = blockIdx.x;
  if (threadIdx.x == 0) {
    unsigned long long m = 0ull;
    for (int j = 0; j < SAMPLE_; ++j) m |= (1ull << (cidx[b * SAMPLE_ + j] & 63));
    int n = 0;
    for (int c = 0; c < NCHUNK; ++c)
      if ((m >> c) & 1ull) sel[n++] = c;
    nsel_s = n;
  }
  __syncthreads();
  const int n = nsel_s;
  for (int s = threadIdx.x; s < SMAX; s += 256) {
    const int k = s >> 7;
    srcT[b * SMAX + s] = (k < n) ? (sel[k] * CHUNK_ + (s & 127)) : -1;
  }
}

// ---------------------------------------------------------------------------
// Kernel 2: W (D,H) fp32 -> Wt (H,D) fp16  (LDS-tiled transpose).
// ---------------------------------------------------------------------------
__global__ __launch_bounds__(256) void k_wt(const float* __restrict__ W,
                                            unsigned short* __restrict__ Wt) {
  __shared__ unsigned short tile[64][65];  // [h][d], padded
  const int hb = blockIdx.x * 64;
  const int db = blockIdx.y * 64;
  const int c = threadIdx.x & 63;
  const int r0 = threadIdx.x >> 6;
#pragma unroll
  for (int j = 0; j < 16; ++j) {
    const int r = r0 + j * 4;  // d offset
    tile[c][r] = f2h(W[(size_t)(db + r) * NH + hb + c]);
  }
  __syncthreads();
#pragma unroll
  for (int j = 0; j < 16; ++j) {
    const int r = r0 + j * 4;  // h offset
    Wt[(size_t)(hb + r) * ND + db + c] = tile[r][c];
  }
}

// ---------------------------------------------------------------------------
// Kernel 3: gather selected rows of data, fp32 -> fp16, materialize A (M x K).
// 2 rows per block, 8 elements per thread (16 B stores). Invalid rows skipped
// (their tiles never read A).
// ---------------------------------------------------------------------------
__global__ __launch_bounds__(256) void k_gatherA(const float* __restrict__ data,
                                                 const int* __restrict__ srcT,
                                                 unsigned short* __restrict__ A) {
  const int row = blockIdx.x * 2 + (threadIdx.x >> 7);  // 0..16383
  const int t = srcT[row];                               // block-uniform validity
  if (t < 0) return;
  const int b = row >> 11;
  const int col = (threadIdx.x & 127) * 8;
  const float4* src = (const float4*)(data + ((size_t)b * NT + t) * ND + col);
  const float4 v0 = src[0];
  const float4 v1 = src[1];
  ushort8 o;
  o[0] = f2h(v0.x); o[1] = f2h(v0.y); o[2] = f2h(v0.z); o[3] = f2h(v0.w);
  o[4] = f2h(v1.x); o[5] = f2h(v1.y); o[6] = f2h(v1.z); o[7] = f2h(v1.w);
  *(ushort8*)(A + (size_t)row * ND + col) = o;
}

// ---------------------------------------------------------------------------
// Kernel 4: GEMM C = A @ Wt^T with fused epilogue. 128x128 tile, BK=64,
// mfma_f32_16x16x32_f16, global_load_lds width=16, XOR-swizzled LDS
// (source-side swizzle: LDS chunk (row, c) holds global k-chunk c ^ (row&7)),
// tile-uniform invalid fast path (stream zeros).
// ---------------------------------------------------------------------------
__device__ __forceinline__ void gl_lds16(const unsigned short* g, unsigned short* l) {
  __builtin_amdgcn_global_load_lds(
      (const __attribute__((address_space(1))) unsigned int*)g,
      (__attribute__((address_space(3))) unsigned int*)l, 16, 0, 0);
}

__global__ __launch_bounds__(256) void k_gemm(const unsigned short* __restrict__ A,
                                              const unsigned short* __restrict__ Bt,
                                              const float* __restrict__ bias,
                                              const int* __restrict__ srcT,
                                              float* __restrict__ out) {
  __shared__ unsigned short As[128 * BK];  // 16 KB, swizzled row-major [m][k]
  __shared__ unsigned short Bs[128 * BK];  // 16 KB, swizzled row-major [n][k]

  const int tid = threadIdx.x;
  const int tile_n = blockIdx.x & 7;   // NH/128 = 8
  const int tile_m = blockIdx.x >> 3;  // MROWS/128 = 128
  const int t0 = srcT[tile_m * 128];   // uniform: tile == one chunk slot

  if (t0 < 0) {
    // whole tile invalid -> zeros, coalesced float4 stores
    const int r = tid >> 1;
    const int cb = (tid & 1) * 64;
    float4 z = make_float4(0.f, 0.f, 0.f, 0.f);
    float* o = out + (size_t)(tile_m * 128 + r) * NH + tile_n * 128 + cb;
#pragma unroll
    for (int v = 0; v < 16; ++v) *(float4*)(o + 4 * v) = z;
    return;
  }

  const int lane = tid & 63;
  const int w = tid >> 6;
  const int wm = w & 1;
  const int wn = w >> 1;

  floatx4 acc[4][4];
#pragma unroll
  for (int i = 0; i < 4; ++i)
#pragma unroll
    for (int j = 0; j < 4; ++j) acc[i][j] = (floatx4){0.f, 0.f, 0.f, 0.f};

  // --- staging addressing -------------------------------------------------
  // Per wave-call, lane l writes LDS chunk base+l. LDS chunk L: row = L>>3,
  // lds-chunk c = L&7, sourced from global k-chunk g = c ^ (row&7).
  // With row = (w*4+q)*8 + (l>>3): row&7 = l>>3, so g = (l&7) ^ (l>>3).
  const int srow = lane >> 3;                       // 0..7 (within 8-row group)
  const int g8 = (((lane & 7) ^ srow) * 8);         // k offset in halfs
  const unsigned short* gA0 =
      A + (size_t)(tile_m * 128 + w * 32 + srow) * ND + g8;
  const unsigned short* gB0 =
      Bt + (size_t)(tile_n * 128 + w * 32 + srow) * ND + g8;
  unsigned short* lA0 = As + w * 2048;  // (w*4)*64 chunks * 8 halfs
  unsigned short* lB0 = Bs + w * 2048;

  // --- fragment LDS addresses (K-loop invariant) --------------------------
  // A[m][k0..k0+8), k-chunk g = (lane>>4) + s*4, lds chunk = g ^ (m&7),
  // m&7 == lane&7 here. Byte-free: half offsets.
  const int mrow = wm * 64 + (lane & 15);
  const int nrow = wn * 64 + (lane & 15);
  const int x7 = lane & 7;
  int aoff[4][2], boff[4][2];
#pragma unroll
  for (int i = 0; i < 4; ++i)
#pragma unroll
    for (int s = 0; s < 2; ++s) {
      const int c = ((lane >> 4) + s * 4) ^ x7;
      aoff[i][s] = (mrow + i * 16) * BK + c * 8;
      boff[i][s] = (nrow + i * 16) * BK + c * 8;
    }

  for (int kk = 0; kk < ND; kk += BK) {
    __syncthreads();
#pragma unroll
    for (int q = 0; q < 4; ++q) gl_lds16(gA0 + (size_t)q * 8 * ND + kk, lA0 + q * 512);
#pragma unroll
    for (int q = 0; q < 4; ++q) gl_lds16(gB0 + (size_t)q * 8 * ND + kk, lB0 + q * 512);
    __syncthreads();

#pragma unroll
    for (int s = 0; s < 2; ++s) {
      half8 af[4], bf[4];
#pragma unroll
      for (int i = 0; i < 4; ++i) af[i] = *(const half8*)(As + aoff[i][s]);
#pragma unroll
      for (int j = 0; j < 4; ++j) bf[j] = *(const half8*)(Bs + boff[j][s]);
#pragma unroll
      for (int i = 0; i < 4; ++i)
#pragma unroll
        for (int j = 0; j < 4; ++j)
          acc[i][j] = __builtin_amdgcn_mfma_f32_16x16x32_f16(af[i], bf[j], acc[i][j], 0, 0, 0);
    }
  }

  // --- epilogue. C/D layout: col = lane&15, row = (lane>>4)*4 + reg. ------
  const float scale = 11.313708498984761f;        // sqrt(128)
  const float nl = -9.210340371976184f / 1024.f;  // -ln(10000)/H
  const int colq = lane & 15;
  const int rq = (lane >> 4) * 4;
#pragma unroll
  for (int j = 0; j < 4; ++j) {
    const int gh = tile_n * 128 + wn * 64 + j * 16 + colq;
    const float freq = __expf((float)(gh & ~1) * nl);
    const float bv = bias[gh];
#pragma unroll
    for (int i = 0; i < 4; ++i) {
      const int lrow0 = wm * 64 + i * 16 + rq;
#pragma unroll
      for (int r = 0; r < 4; ++r) {
        const int lrow = lrow0 + r;
        const float arg = (float)(t0 + lrow) * freq;
        const float pe = (gh & 1) ? __cosf(arg) : __sinf(arg);
        out[(size_t)(tile_m * 128 + lrow) * NH + gh] =
            (acc[i][j][r] + bv + pe) * scale;
      }
    }
  }
}

// ---------------------------------------------------------------------------
extern "C" void kernel_launch(void* const* d_in, const int* in_sizes, int n_in,
                              void* d_out, int out_size, void* d_ws, size_t ws_size,
                              hipStream_t stream) {
  // inputs: state (unused), data, W, b, chunk_idx
  const float* data = (const float*)d_in[1];
  const float* W = (const float*)d_in[2];
  const float* bias = (const float*)d_in[3];
  const int* cidx = (const int*)d_in[4];
  float* out = (float*)d_out;

  char* ws = (char*)d_ws;
  int* srcT = (int*)ws;                                                // 64 KB
  unsigned short* Wt = (unsigned short*)(ws + (64 << 10));             // 2 MB
  unsigned short* A = (unsigned short*)(ws + (64 << 10) + (2 << 20));  // 32 MB

  k_select<<<NB, 256, 0, stream>>>(cidx, srcT);
  k_wt<<<dim3(NH / 64, ND / 64), 256, 0, stream>>>(W, Wt);
  k_gatherA<<<MROWS / 2, 256, 0, stream>>>(data, srcT, A);
  k_gemm<<<(MROWS / 128) * (NH / 128), 256, 0, stream>>>(A, Wt, bias, srcT, out);
}

// Round 3
// 377.523 us; speedup vs baseline: 1.0609x; 1.0201x over previous
//
#include <hip/hip_runtime.h>
#include <hip/hip_fp16.h>
#include <math.h>

// Problem constants (fixed by setup_inputs)
#define NB 8
#define NT 8192
#define ND 1024
#define NH 1024
#define CHUNK_ 128
#define SAMPLE_ 16
#define NCHUNK 64          // NT / CHUNK
#define SMAX 2048          // SAMPLE * CHUNK
#define MROWS (NB * SMAX)  // 16384
#define BK 64              // K-tile (halfs); rows are 128 B -> 8 x 16B chunks

typedef _Float16 half8 __attribute__((ext_vector_type(8)));
typedef float floatx4 __attribute__((ext_vector_type(4)));
typedef unsigned short ushort8 __attribute__((ext_vector_type(8)));

__device__ __forceinline__ unsigned short f2h(float f) {
  return __half_as_ushort(__float2half(f));
}

// Derive start time index of chunk-slot `slot` for batch `b` from cidx.
// Returns -1 if slot >= number of distinct selected chunks. Wave-uniform
// inputs -> compiler scalarizes (s_ ops only).
__device__ __forceinline__ int slot_t0(const int* __restrict__ cidx, int b, int slot) {
  unsigned long long m = 0ull;
#pragma unroll
  for (int j = 0; j < SAMPLE_; ++j) m |= (1ull << (cidx[b * SAMPLE_ + j] & 63));
  unsigned long long tmp = m;
  for (int s = 0; s < slot; ++s) tmp &= (tmp - 1ull);  // clear `slot` lowest bits
  if (tmp == 0ull) return -1;
  return (__ffsll((unsigned long long)tmp) - 1) * CHUNK_;
}

// ---------------------------------------------------------------------------
// Kernel 1 (fused prep): blocks [0,256) transpose+convert W -> Wt fp16;
// blocks [256, 256+8192) gather 2 selected data rows each -> A fp16.
// Roles are block-uniform; gather blocks derive their chunk from cidx
// directly (no k_select kernel / srcT array).
// ---------------------------------------------------------------------------
__global__ __launch_bounds__(256) void k_prep(const float* __restrict__ W,
                                              const float* __restrict__ data,
                                              const int* __restrict__ cidx,
                                              unsigned short* __restrict__ Wt,
                                              unsigned short* __restrict__ A) {
  if (blockIdx.x < 256) {
    // ---- W transpose: W (D,H) fp32 -> Wt (H,D) fp16 ----
    __shared__ unsigned short tile[64][65];  // [h][d], padded
    const int hb = (blockIdx.x & 15) * 64;
    const int db = (blockIdx.x >> 4) * 64;
    const int c = threadIdx.x & 63;
    const int r0 = threadIdx.x >> 6;
#pragma unroll
    for (int j = 0; j < 16; ++j) {
      const int r = r0 + j * 4;  // d offset
      tile[c][r] = f2h(W[(size_t)(db + r) * NH + hb + c]);
    }
    __syncthreads();
#pragma unroll
    for (int j = 0; j < 16; ++j) {
      const int r = r0 + j * 4;  // h offset
      Wt[(size_t)(hb + r) * ND + db + c] = tile[r][c];
    }
    return;
  }

  // ---- gather: 2 consecutive rows (same chunk slot) per block ----
  const int row0 = (blockIdx.x - 256) * 2;  // 0..16382, even
  const int b = row0 >> 11;
  const int slot = (row0 >> 7) & 15;
  const int t0 = slot_t0(cidx, b, slot);
  if (t0 < 0) return;  // rows invalid -> their tile is never read

  const int sub = threadIdx.x >> 7;  // 0/1: which of the two rows
  const int row = row0 + sub;
  const int t = t0 + (row0 & 127) + sub;
  const int col = (threadIdx.x & 127) * 8;
  const float4* src = (const float4*)(data + ((size_t)b * NT + t) * ND + col);
  const float4 v0 = src[0];
  const float4 v1 = src[1];
  ushort8 o;
  o[0] = f2h(v0.x); o[1] = f2h(v0.y); o[2] = f2h(v0.z); o[3] = f2h(v0.w);
  o[4] = f2h(v1.x); o[5] = f2h(v1.y); o[6] = f2h(v1.z); o[7] = f2h(v1.w);
  *(ushort8*)(A + (size_t)row * ND + col) = o;
}

// ---------------------------------------------------------------------------
// Kernel 2: GEMM C = A @ Wt^T with fused epilogue (bias + sinusoidal PE,
// *sqrt(128)). 128x128 tile, BK=64, mfma_f32_16x16x32_f16, global_load_lds
// width=16, XOR-swizzled LDS, tile-uniform invalid fast path (stream zeros).
// Chunk start t0 derived from cidx in-block (scalar path).
// ---------------------------------------------------------------------------
__device__ __forceinline__ void gl_lds16(const unsigned short* g, unsigned short* l) {
  __builtin_amdgcn_global_load_lds(
      (const __attribute__((address_space(1))) unsigned int*)g,
      (__attribute__((address_space(3))) unsigned int*)l, 16, 0, 0);
}

__global__ __launch_bounds__(256) void k_gemm(const unsigned short* __restrict__ A,
                                              const unsigned short* __restrict__ Bt,
                                              const float* __restrict__ bias,
                                              const int* __restrict__ cidx,
                                              float* __restrict__ out) {
  __shared__ unsigned short As[128 * BK];  // 16 KB, swizzled row-major [m][k]
  __shared__ unsigned short Bs[128 * BK];  // 16 KB, swizzled row-major [n][k]

  const int tid = threadIdx.x;
  const int tile_n = blockIdx.x & 7;   // NH/128 = 8
  const int tile_m = blockIdx.x >> 3;  // MROWS/128 = 128; == one chunk slot
  const int t0 = slot_t0(cidx, tile_m >> 4, tile_m & 15);

  if (t0 < 0) {
    // whole tile invalid -> zeros, coalesced float4 stores
    const int r = tid >> 1;
    const int cb = (tid & 1) * 64;
    float4 z = make_float4(0.f, 0.f, 0.f, 0.f);
    float* o = out + (size_t)(tile_m * 128 + r) * NH + tile_n * 128 + cb;
#pragma unroll
    for (int v = 0; v < 16; ++v) *(float4*)(o + 4 * v) = z;
    return;
  }

  const int lane = tid & 63;
  const int w = tid >> 6;
  const int wm = w & 1;
  const int wn = w >> 1;

  floatx4 acc[4][4];
#pragma unroll
  for (int i = 0; i < 4; ++i)
#pragma unroll
    for (int j = 0; j < 4; ++j) acc[i][j] = (floatx4){0.f, 0.f, 0.f, 0.f};

  // --- staging addressing -------------------------------------------------
  // Per wave-call, lane l writes LDS chunk base+l. LDS chunk L: row = L>>3,
  // lds-chunk c = L&7, sourced from global k-chunk g = c ^ (row&7).
  const int srow = lane >> 3;                // 0..7 (within 8-row group)
  const int g8 = (((lane & 7) ^ srow) * 8);  // k offset in halfs
  const unsigned short* gA0 =
      A + (size_t)(tile_m * 128 + w * 32 + srow) * ND + g8;
  const unsigned short* gB0 =
      Bt + (size_t)(tile_n * 128 + w * 32 + srow) * ND + g8;
  unsigned short* lA0 = As + w * 2048;
  unsigned short* lB0 = Bs + w * 2048;

  // --- fragment LDS addresses (K-loop invariant) --------------------------
  const int mrow = wm * 64 + (lane & 15);
  const int nrow = wn * 64 + (lane & 15);
  const int x7 = lane & 7;
  int aoff[4][2], boff[4][2];
#pragma unroll
  for (int i = 0; i < 4; ++i)
#pragma unroll
    for (int s = 0; s < 2; ++s) {
      const int c = ((lane >> 4) + s * 4) ^ x7;
      aoff[i][s] = (mrow + i * 16) * BK + c * 8;
      boff[i][s] = (nrow + i * 16) * BK + c * 8;
    }

  for (int kk = 0; kk < ND; kk += BK) {
    __syncthreads();
#pragma unroll
    for (int q = 0; q < 4; ++q) gl_lds16(gA0 + (size_t)q * 8 * ND + kk, lA0 + q * 512);
#pragma unroll
    for (int q = 0; q < 4; ++q) gl_lds16(gB0 + (size_t)q * 8 * ND + kk, lB0 + q * 512);
    __syncthreads();

#pragma unroll
    for (int s = 0; s < 2; ++s) {
      half8 af[4], bf[4];
#pragma unroll
      for (int i = 0; i < 4; ++i) af[i] = *(const half8*)(As + aoff[i][s]);
#pragma unroll
      for (int j = 0; j < 4; ++j) bf[j] = *(const half8*)(Bs + boff[j][s]);
#pragma unroll
      for (int i = 0; i < 4; ++i)
#pragma unroll
        for (int j = 0; j < 4; ++j)
          acc[i][j] = __builtin_amdgcn_mfma_f32_16x16x32_f16(af[i], bf[j], acc[i][j], 0, 0, 0);
    }
  }

  // --- epilogue. C/D layout: col = lane&15, row = (lane>>4)*4 + reg. ------
  const float scale = 11.313708498984761f;        // sqrt(128)
  const float nl = -9.210340371976184f / 1024.f;  // -ln(10000)/H
  const int colq = lane & 15;
  const int rq = (lane >> 4) * 4;
#pragma unroll
  for (int j = 0; j < 4; ++j) {
    const int gh = tile_n * 128 + wn * 64 + j * 16 + colq;
    const float freq = __expf((float)(gh & ~1) * nl);
    const float bv = bias[gh];
#pragma unroll
    for (int i = 0; i < 4; ++i) {
      const int lrow0 = wm * 64 + i * 16 + rq;
#pragma unroll
      for (int r = 0; r < 4; ++r) {
        const int lrow = lrow0 + r;
        const float arg = (float)(t0 + lrow) * freq;
        const float pe = (gh & 1) ? __cosf(arg) : __sinf(arg);
        out[(size_t)(tile_m * 128 + lrow) * NH + gh] =
            (acc[i][j][r] + bv + pe) * scale;
      }
    }
  }
}

// ---------------------------------------------------------------------------
extern "C" void kernel_launch(void* const* d_in, const int* in_sizes, int n_in,
                              void* d_out, int out_size, void* d_ws, size_t ws_size,
                              hipStream_t stream) {
  // inputs: state (unused), data, W, b, chunk_idx
  const float* data = (const float*)d_in[1];
  const float* W = (const float*)d_in[2];
  const float* bias = (const float*)d_in[3];
  const int* cidx = (const int*)d_in[4];
  float* out = (float*)d_out;

  char* ws = (char*)d_ws;
  unsigned short* Wt = (unsigned short*)ws;                 // 2 MB
  unsigned short* A = (unsigned short*)(ws + (2 << 20));    // 32 MB

  k_prep<<<256 + MROWS / 2, 256, 0, stream>>>(W, data, cidx, Wt, A);
  k_gemm<<<(MROWS / 128) * (NH / 128), 256, 0, stream>>>(A, Wt, bias, cidx, out);
}